// Round 9
// baseline (183.750 us; speedup 1.0000x reference)
//
#include <hip/hip_runtime.h>
#include <stdint.h>

// ---------------------------------------------------------------------------
// WeightGenerator_V4, round 12: resubmit of r11 (single fused kernel) with
// OOB-pointer-formation hardening in phase-1 (clamped addresses; predicate
// unchanged -> identical arithmetic). r8 bench was an infra failure
// ("container failed twice"), no verdict; audit found no hang mechanism.
//   - Deletes k1: each block recomputes its pixel's gate/conv in phase-1,
//     hidden under the already-issued y HBM loads.
//   - w_lin consumed fp32 -> bf16 in-register (cvt8) at the prefetch
//     consumer; no workspace passes at all.
//   - Then r9's proven pipeline verbatim: 4-round y staging via swizzled
//     scratch, wave-private Wd regions, barrier-free K-loop, 2-deep
//     wlin+bias register prefetch, plain scalar epilogue stores.
//   512 blocks x 512 thr, LDS 49.4 KB.
// ---------------------------------------------------------------------------

typedef __attribute__((ext_vector_type(8))) short short8;
typedef __attribute__((ext_vector_type(4))) float f32x4;

#define BN_EPS 1e-5f

__device__ __forceinline__ unsigned short f2bf(float f) {
  unsigned u = __float_as_uint(f);
  return (unsigned short)((u + 0x8000u) >> 16);
}
__device__ __forceinline__ unsigned pk2bf(float a, float b) {
  unsigned ua = __float_as_uint(a), ub = __float_as_uint(b);
  return ((ua + 0x8000u) >> 16) | ((ub + 0x8000u) & 0xFFFF0000u);
}
__device__ __forceinline__ short8 cvt8(float4 a, float4 b) {
  union { uint4 u; short8 s; } r;
  r.u.x = pk2bf(a.x, a.y); r.u.y = pk2bf(a.z, a.w);
  r.u.z = pk2bf(b.x, b.y); r.u.w = pk2bf(b.z, b.w);
  return r.s;
}

// =====================  fused kernel  =====================
// LDS: Ylds 32 KB ([64 pix][32 granules of 8c] bf16; phase-1 alias: x-window
//      [32 grp][4 ch][49] f32) + dyn 16.6 KB (phase-1: xcen/xrw/f0/gs;
//      staging: scratch [64][65] f32; K-loop: 8 x 2 KB wave-private Wd).
__global__ __launch_bounds__(512, 4) void k_fused(
    const float* __restrict__ x, const float* __restrict__ y,
    const float* __restrict__ w_cr, const float* __restrict__ b_cr,
    const float* __restrict__ w_dw3, const float* __restrict__ b_dw3,
    const float* __restrict__ w_dw7, const float* __restrict__ b_dw7,
    const float* __restrict__ w_gate, const float* __restrict__ b_gate,
    const float* __restrict__ bn_gamma, const float* __restrict__ bn_beta,
    const float* __restrict__ bn_mean, const float* __restrict__ bn_var,
    const float* __restrict__ sr_scale, const float* __restrict__ sr_bias,
    const float* __restrict__ w_lin, const float* __restrict__ b_lin,
    float* __restrict__ out)
{
  __shared__ __align__(16) short Ylds[16384];
  __shared__ __align__(16) char dyn[16640];
  float* xwf    = (float*)Ylds;                  // phase1: [32][4][49] f32
  float* xcen   = (float*)dyn;                   // [256]
  float* xrw    = (float*)(dyn + 1024);          // [32][25]
  float* f0buf  = (float*)(dyn + 4224);          // [128]
  float* gsbuf  = (float*)(dyn + 4736);          // [128]
  float* scratch = (float*)dyn;                  // staging [64][65]
  short* wdbase  = (short*)dyn;                  // 8 x [32 ep][32 c] bf16

  int phys = blockIdx.x;
  int blk = (phys & 7) * 64 + (phys >> 3);       // XCD-contiguous patches
  int b = blk >> 8, pf_ = (blk >> 4) & 15, pg_ = blk & 15;
  int tid = threadIdx.x;
  int wave = tid >> 6, lane = tid & 63;
  int quad = lane >> 4, l16 = lane & 15;
  int geff = l16 & 7, jsel = l16 >> 3;

  const float* yb = y + b * 4194304 + (pf_ * 8) * 128 + pg_ * 8;

  // ---- issue y loads for staging rounds 0,1 (latency shadow for phase 1) --
  int c32 = tid >> 4, pf = tid & 15;             // 32 c x 16 pixel-float4
  int pxo = (pf >> 1) * 128 + (pf & 1) * 4;
  float4 yv[2][2];
  #pragma unroll
  for (int s = 0; s < 2; ++s)
    #pragma unroll
    for (int it = 0; it < 2; ++it)
      yv[s][it] = *(const float4*)(yb + (s * 64 + it * 32 + c32) * 16384 + pxo);

  // =================== phase 1: in-block gate + conv/dw ===================
  // xcen = x[b, :, pf_, pg_]
  if (tid < 256) xcen[tid] = x[b * 65536 + tid * 256 + pf_ * 16 + pg_];

  for (int h2 = 0; h2 < 2; ++h2) {
    // ---- x 7x7 window for 32 channel-groups (zero-padded) ----
    for (int t2 = tid; t2 < 896; t2 += 512) {
      int grp = t2 / 28;
      int rem = t2 - grp * 28;
      int ch = rem / 7, row = rem - (rem / 7) * 7;
      int cg = (h2 * 32 + grp) * 4 + ch;
      int gy = pf_ - 3 + row;
      int gyc = min(max(gy, 0), 15);             // clamped addr; predicate gates value
      const float* xrow = x + b * 65536 + cg * 256 + gyc * 16;
      float* wrow = xwf + (grp * 4 + ch) * 49 + row * 7;
      #pragma unroll
      for (int kx = 0; kx < 7; ++kx) {
        int gx = pg_ - 3 + kx;
        int gxc = min(max(gx, 0), 15);
        float v = xrow[gxc];
        wrow[kx] = (gy >= 0 && gy < 16 && gx >= 0 && gx < 16) ? v : 0.f;
      }
    }
    __syncthreads();
    // ---- grouped 3x3 conv: xr on the 5x5 neighborhood ----
    for (int t2 = tid; t2 < 800; t2 += 512) {
      int grp = t2 / 25, pos = t2 - (t2 / 25) * 25;
      int py = pos / 5, px = pos - (pos / 5) * 5;
      int cr = h2 * 32 + grp;
      int xy = pf_ - 2 + py, xx = pg_ - 2 + px;
      float v = 0.f;
      if (xy >= 0 && xy < 16 && xx >= 0 && xx < 16) {
        v = b_cr[cr];
        #pragma unroll
        for (int ii = 0; ii < 4; ++ii) {
          const float* wp = w_cr + (cr * 4 + ii) * 9;
          const float* xw = xwf + (grp * 4 + ii) * 49;
          #pragma unroll
          for (int ky = 0; ky < 3; ++ky)
            #pragma unroll
            for (int kx = 0; kx < 3; ++kx)
              v += wp[ky * 3 + kx] * xw[(py + ky) * 7 + (px + kx)];
        }
      }
      xrw[grp * 25 + pos] = v;
    }
    __syncthreads();
    // ---- dw3 (center of 5x5) and dw5 (full 5x5) ----
    if (tid < 64) {
      int grp = tid >> 1, which = tid & 1, cr = h2 * 32 + grp;
      const float* xr0 = xrw + grp * 25;
      if (which == 0) {
        float v = b_dw3[cr];
        const float* wp = w_dw3 + cr * 9;
        #pragma unroll
        for (int ky = 0; ky < 3; ++ky)
          #pragma unroll
          for (int kx = 0; kx < 3; ++kx)
            v += wp[ky * 3 + kx] * xr0[(ky + 1) * 5 + (kx + 1)];
        f0buf[cr] = v;
      } else {
        float v = b_dw7[cr];
        const float* wp = w_dw7 + cr * 25;
        #pragma unroll
        for (int ky = 0; ky < 5; ++ky)
          #pragma unroll
          for (int kx = 0; kx < 5; ++kx)
            v += wp[ky * 5 + kx] * xr0[ky * 5 + kx];
        f0buf[64 + cr] = v;
      }
    }
    __syncthreads();
  }

  // ---- gate: 1x1 conv + BN + StarReLU (identical arithmetic to old k1) ----
  {
    int o = tid >> 2, ol = tid & 3;              // 128 outputs x 4 lanes
    const float4* wg4 = (const float4*)w_gate;
    const float4* xc4 = (const float4*)xcen;
    float acc = 0.f;
    #pragma unroll
    for (int k = 0; k < 16; ++k) {
      int j = k * 4 + ol;
      float4 wv = wg4[o * 64 + j];
      float4 xv = xc4[j];
      acc += wv.x * xv.x + wv.y * xv.y + wv.z * xv.z + wv.w * xv.w;
    }
    acc += __shfl_xor(acc, 1);
    acc += __shfl_xor(acc, 2);
    float inv = bn_gamma[o] * rsqrtf(bn_var[o] + BN_EPS);
    float gg = (acc + b_gate[o] - bn_mean[o]) * inv + bn_beta[o];
    gg = fmaxf(gg, 0.f);
    gg = sr_scale[0] * gg * gg + sr_bias[0];
    if (ol == 0) gsbuf[o] = gg;
  }
  __syncthreads();

  // ---- f0/gs -> registers (before staging clobbers dyn) ----
  bool bval = (jsel == (quad >> 1));
  const float* f0p = f0buf + geff * 16 + (quad & 1) * 8;
  const float* gsp = gsbuf + geff * 16 + (quad & 1) * 8;
  float4 f0a = *(const float4*)f0p, f0b = *(const float4*)(f0p + 4);
  float4 gsa = *(const float4*)gsp, gsb = *(const float4*)(gsp + 4);
  __syncthreads();

  // ---- wlin(fp32) + b_lin prefetch for chunks 0,1 (slot = chunk&1) ----
  float4 awf[2][2][2][2];                        // [slot][jj][hh][half]
  float4 bl[2][2][2];
  #pragma unroll
  for (int s = 0; s < 2; ++s)
    #pragma unroll
    for (int jj = 0; jj < 2; ++jj) {
      int jA = wave * 4 + jj * 2 + (quad >> 1);
      int jD = wave * 4 + jj * 2 + jsel;
      #pragma unroll
      for (int hh = 0; hh < 2; ++hh) {
        int c0 = s * 32 + hh * 16;
        const float* wp = w_lin + (jA * 256 + c0 + l16) * 16 + (quad & 1) * 8;
        awf[s][jj][hh][0] = *(const float4*)wp;
        awf[s][jj][hh][1] = *(const float4*)(wp + 4);
        bl[s][jj][hh] = *(const float4*)(b_lin + jD * 256 + c0 + quad * 4);
      }
    }

  // ---- stage Y: 4 rounds of 64 channels through scratch ----
  #pragma unroll
  for (int sch = 0; sch < 4; ++sch) {
    #pragma unroll
    for (int it = 0; it < 2; ++it)
      *(float4*)&scratch[(it * 32 + c32) * 65 + pf * 4] = yv[sch & 1][it];
    if (sch < 2) {                               // issue round sch+2 loads
      #pragma unroll
      for (int it = 0; it < 2; ++it)
        yv[sch & 1][it] = *(const float4*)(yb + ((sch + 2) * 64 + it * 32 + c32) * 16384 + pxo);
    }
    __syncthreads();
    {
      int pix = tid & 63, cg = tid >> 6;         // 64 pix x 8 c-groups of 8
      float s0 = scratch[(cg * 8 + 0) * 65 + pix];
      float s1 = scratch[(cg * 8 + 1) * 65 + pix];
      float s2 = scratch[(cg * 8 + 2) * 65 + pix];
      float s3 = scratch[(cg * 8 + 3) * 65 + pix];
      float s4 = scratch[(cg * 8 + 4) * 65 + pix];
      float s5 = scratch[(cg * 8 + 5) * 65 + pix];
      float s6 = scratch[(cg * 8 + 6) * 65 + pix];
      float s7 = scratch[(cg * 8 + 7) * 65 + pix];
      uint4 pk;
      pk.x = pk2bf(s0, s1); pk.y = pk2bf(s2, s3);
      pk.z = pk2bf(s4, s5); pk.w = pk2bf(s6, s7);
      int chunk = sch * 8 + cg;                  // 8-ch group id [0,32)
      int physc = chunk ^ (pix & 15);            // read-optimal swizzle
      *(uint4*)&Ylds[pix * 256 + physc * 8] = pk;
    }
    __syncthreads();
  }

  // ---- xc fragment: B[k][n=jsel*8+geff] = xc[geff][k%16] iff k>>4==jsel ----
  short8 bx = {0, 0, 0, 0, 0, 0, 0, 0};
  if (bval) {
    bx[0] = (short)f2bf(f0a.x * gsa.x); bx[1] = (short)f2bf(f0a.y * gsa.y);
    bx[2] = (short)f2bf(f0a.z * gsa.z); bx[3] = (short)f2bf(f0a.w * gsa.w);
    bx[4] = (short)f2bf(f0b.x * gsb.x); bx[5] = (short)f2bf(f0b.y * gsb.y);
    bx[6] = (short)f2bf(f0b.z * gsb.z); bx[7] = (short)f2bf(f0b.w * gsb.w);
  }

  f32x4 acc[2][4];
  #pragma unroll
  for (int et = 0; et < 2; ++et)
    #pragma unroll
    for (int nt = 0; nt < 4; ++nt)
      acc[et][nt] = {0.f, 0.f, 0.f, 0.f};

  // ---- per-wave Wd region: [32 ep][32 c] bf16, ep = geff*4 + jj*2 + jsel ----
  short* wdw = wdbase + wave * 1024;

  // gen: wave w produces jD = 4w + jj*2 + jsel (all 8 geff) -- wave-private.
  auto gen_chunk = [&](int cc, int slot) {
    #pragma unroll
    for (int jj = 0; jj < 2; ++jj) {
      int ep = geff * 4 + jj * 2 + jsel;
      int gx = ((ep >> 2) & 3) ^ (ep & 3);
      #pragma unroll
      for (int hh = 0; hh < 2; ++hh) {
        float4 blv = bl[slot][jj][hh];
        f32x4 cin = {blv.x, blv.y, blv.z, blv.w};
        short8 aws = cvt8(awf[slot][jj][hh][0], awf[slot][jj][hh][1]);
        f32x4 d = __builtin_amdgcn_mfma_f32_16x16x32_bf16(aws, bx, cin, 0, 0, 0);
        uint2 pk;
        pk.x = pk2bf(d[0], d[1]);
        pk.y = pk2bf(d[2], d[3]);
        int q16 = (hh * 2 + (quad >> 1)) ^ gx;
        *(uint2*)&wdw[ep * 32 + q16 * 8 + (quad & 1) * 4] = pk;
      }
    }
  };

  gen_chunk(0, 0);  // scratch alias free after last staging barrier

  // ---- BARRIER-FREE K-loop: per-wave DS ordering protects wdw reuse ----
  #pragma unroll
  for (int cc = 0; cc < 8; ++cc) {
    short8 A2[2], Bf[4];
    #pragma unroll
    for (int et = 0; et < 2; ++et) {
      int ep = (l16 & 7) * 4 + et * 2 + (l16 >> 3);
      int gx = ((ep >> 2) & 3) ^ (ep & 3);
      A2[et] = *(const short8*)&wdw[ep * 32 + (quad ^ gx) * 8];
    }
    int chunkY = cc * 4 + quad;
    #pragma unroll
    for (int nt = 0; nt < 4; ++nt) {
      int physc = chunkY ^ l16;                  // pix&15 == l16
      Bf[nt] = *(const short8*)&Ylds[(nt * 16 + l16) * 256 + physc * 8];
    }
    if (cc < 6) {                                // prefetch wlin+bias for cc+2
      #pragma unroll
      for (int jj = 0; jj < 2; ++jj) {
        int jA = wave * 4 + jj * 2 + (quad >> 1);
        int jD = wave * 4 + jj * 2 + jsel;
        #pragma unroll
        for (int hh = 0; hh < 2; ++hh) {
          int c0 = (cc + 2) * 32 + hh * 16;
          const float* wp = w_lin + (jA * 256 + c0 + l16) * 16 + (quad & 1) * 8;
          awf[cc & 1][jj][hh][0] = *(const float4*)wp;
          awf[cc & 1][jj][hh][1] = *(const float4*)(wp + 4);
          bl[cc & 1][jj][hh] = *(const float4*)(b_lin + jD * 256 + c0 + quad * 4);
        }
      }
    }
    if (cc < 7) gen_chunk(cc + 1, (cc + 1) & 1); // DS in-order: after A2 reads
    #pragma unroll
    for (int et = 0; et < 2; ++et)
      #pragma unroll
      for (int nt = 0; nt < 4; ++nt)
        acc[et][nt] = __builtin_amdgcn_mfma_f32_16x16x32_bf16(A2[et], Bf[nt], acc[et][nt], 0, 0, 0);
  }

  // ---- epilogue: lane row m=quad*4+r -> e=(m&7)*32+4*wave+et*2+(m>>3) ----
  float* ob = out + b * 4194304 + (pf_ * 8) * 128 + pg_ * 8;
  #pragma unroll
  for (int et = 0; et < 2; ++et) {
    #pragma unroll
    for (int nt = 0; nt < 4; ++nt) {
      int pix = nt * 16 + l16;
      float* oa = ob + (pix >> 3) * 128 + (pix & 7);
      #pragma unroll
      for (int r = 0; r < 4; ++r) {
        int m = quad * 4 + r;
        int e = (m & 7) * 32 + wave * 4 + et * 2 + (m >> 3);
        oa[e * 16384] = acc[et][nt][r];
      }
    }
  }
}

// ============================  launcher  ============================
extern "C" void kernel_launch(void* const* d_in, const int* in_sizes, int n_in,
                              void* d_out, int out_size, void* d_ws, size_t ws_size,
                              hipStream_t stream) {
  const float* x        = (const float*)d_in[0];
  const float* y        = (const float*)d_in[1];
  const float* w_cr     = (const float*)d_in[2];
  const float* b_cr     = (const float*)d_in[3];
  const float* w_dw3    = (const float*)d_in[4];
  const float* b_dw3    = (const float*)d_in[5];
  const float* w_dw7    = (const float*)d_in[6];
  const float* b_dw7    = (const float*)d_in[7];
  const float* w_gate   = (const float*)d_in[8];
  const float* b_gate   = (const float*)d_in[9];
  const float* bn_gamma = (const float*)d_in[10];
  const float* bn_beta  = (const float*)d_in[11];
  const float* bn_mean  = (const float*)d_in[12];
  const float* bn_var   = (const float*)d_in[13];
  const float* sr_scale = (const float*)d_in[14];
  const float* sr_bias  = (const float*)d_in[15];
  const float* w_lin    = (const float*)d_in[16];
  const float* b_lin    = (const float*)d_in[17];
  float* out = (float*)d_out;

  hipLaunchKernelGGL(k_fused, dim3(512), dim3(512), 0, stream,
                     x, y, w_cr, b_cr, w_dw3, b_dw3, w_dw7, b_dw7,
                     w_gate, b_gate, bn_gamma, bn_beta, bn_mean, bn_var,
                     sr_scale, sr_bias, w_lin, b_lin, out);
}

// Round 10
// 151.344 us; speedup vs baseline: 1.2141x; 1.2141x over previous
//
#include <hip/hip_runtime.h>
#include <stdint.h>

// ---------------------------------------------------------------------------
// WeightGenerator_V4, round 13: REVERT to r9 (round-6 source, best verified:
// total 153.9 us, k2 43.4 us). r10 (nt stores), r11/r12 (full fusion) both
// regressed via L2 write-merge disruption; r9 is the plateau point.
//   k1: gate -> gs; conv+dw3/dw5 -> f0; w_lin -> bf16.
//   k2: 512 blocks (1 patch), 512 thr = 8 waves, LDS 49.4 KB.
//       Wave-private Wd regions + barrier-free K-loop, 2-deep wlin+bias
//       register prefetch, 2-round y double-buffer, swizzled LDS.
// ---------------------------------------------------------------------------

typedef __attribute__((ext_vector_type(8))) short short8;
typedef __attribute__((ext_vector_type(4))) float f32x4;

#define BN_EPS 1e-5f

__device__ __forceinline__ unsigned short f2bf(float f) {
  unsigned u = __float_as_uint(f);
  return (unsigned short)((u + 0x8000u) >> 16);
}
__device__ __forceinline__ unsigned pk2bf(float a, float b) {
  unsigned ua = __float_as_uint(a), ub = __float_as_uint(b);
  return ((ua + 0x8000u) >> 16) | ((ub + 0x8000u) & 0xFFFF0000u);
}

// =====================  k1: gate + conv/dw (role-split)  =====================
__global__ __launch_bounds__(256) void k1_merged(
    const float* __restrict__ x, const float* __restrict__ w_cr,
    const float* __restrict__ b_cr, const float* __restrict__ w_dw3,
    const float* __restrict__ b_dw3, const float* __restrict__ w_dw7,
    const float* __restrict__ b_dw7, const float* __restrict__ w_gate,
    const float* __restrict__ b_gate, const float* __restrict__ bn_gamma,
    const float* __restrict__ bn_beta, const float* __restrict__ bn_mean,
    const float* __restrict__ bn_var, const float* __restrict__ sr_scale,
    const float* __restrict__ sr_bias, const float* __restrict__ w_lin,
    short* __restrict__ wlin_bf, float* __restrict__ f0_out,
    float* __restrict__ gs_out)
{
  __shared__ __align__(16) float xcen[256];   // gate role
  __shared__ __align__(16) float xs[4][256];  // conv role
  __shared__ __align__(16) float xrs[256];    // conv role

  int blk = blockIdx.x;
  int t = threadIdx.x;

  if (blk < 512) {
    // ---------------- gate role: one pixel per block ----------------
    int b = blk >> 8, h = (blk >> 4) & 15, w = blk & 15;
    int pix = (b * 16 + h) * 16 + w;

    { int idx = blk * 256 + t; wlin_bf[idx] = (short)f2bf(w_lin[idx]); }

    xcen[t] = x[b * 65536 + t * 256 + h * 16 + w];
    __syncthreads();

    int wave = t >> 6, lane = t & 63;
    int oq = lane >> 2, ol = lane & 3;          // 16 outputs x 4 lanes
    const float4* wg4 = (const float4*)w_gate;
    const float4* xc4 = (const float4*)xcen;
    float ss = sr_scale[0], sb = sr_bias[0];

    #pragma unroll
    for (int pass = 0; pass < 2; ++pass) {
      int o = wave * 32 + pass * 16 + oq;       // [0,128)
      float acc = 0.f;
      #pragma unroll
      for (int k = 0; k < 16; ++k) {
        int j = k * 4 + ol;                     // float4 index over 256 ch
        float4 wv = wg4[o * 64 + j];            // quad-coalesced 64B lines
        float4 xv = xc4[j];                     // LDS broadcast
        acc += wv.x * xv.x + wv.y * xv.y + wv.z * xv.z + wv.w * xv.w;
      }
      acc += __shfl_xor(acc, 1);
      acc += __shfl_xor(acc, 2);
      float inv = bn_gamma[o] * rsqrtf(bn_var[o] + BN_EPS);
      float gg = (acc + b_gate[o] - bn_mean[o]) * inv + bn_beta[o];
      gg = fmaxf(gg, 0.f);
      gg = ss * gg * gg + sb;
      if (ol == 0) gs_out[pix * 128 + o] = gg;
    }
  } else {
    // ---------------- conv role: one (b, cr) channel-image ----------------
    int cb = blk - 512;
    int b = cb >> 6, cr = cb & 63;
    {
      int ch = t >> 6, off = (t & 63) * 4;
      float4 v = *(const float4*)(x + b * 65536 + (cr * 4 + ch) * 256 + off);
      *(float4*)&xs[ch][off] = v;
    }
    __syncthreads();
    int h = t >> 4, w = t & 15;
    float a = b_cr[cr];
    #pragma unroll
    for (int ii = 0; ii < 4; ++ii) {
      const float* wp = w_cr + (cr * 4 + ii) * 9;
      #pragma unroll
      for (int ky = 0; ky < 3; ++ky) {
        int gy = h + ky - 1;
        #pragma unroll
        for (int kx = 0; kx < 3; ++kx) {
          int gx = w + kx - 1;
          float v = (gy >= 0 && gy < 16 && gx >= 0 && gx < 16) ? xs[ii][gy * 16 + gx] : 0.f;
          a += wp[ky * 3 + kx] * v;
        }
      }
    }
    xrs[t] = a;
    __syncthreads();

    float f3 = b_dw3[cr];
    {
      const float* wp = w_dw3 + cr * 9;
      #pragma unroll
      for (int ky = 0; ky < 3; ++ky) {
        int gy = h + ky - 1;
        #pragma unroll
        for (int kx = 0; kx < 3; ++kx) {
          int gx = w + kx - 1;
          float v = (gy >= 0 && gy < 16 && gx >= 0 && gx < 16) ? xrs[gy * 16 + gx] : 0.f;
          f3 += wp[ky * 3 + kx] * v;
        }
      }
    }
    float f5 = b_dw7[cr];
    {
      const float* wp = w_dw7 + cr * 25;
      #pragma unroll
      for (int ky = 0; ky < 5; ++ky) {
        int gy = h + ky - 2;
        #pragma unroll
        for (int kx = 0; kx < 5; ++kx) {
          int gx = w + kx - 2;
          float v = (gy >= 0 && gy < 16 && gx >= 0 && gx < 16) ? xrs[gy * 16 + gx] : 0.f;
          f5 += wp[ky * 5 + kx] * v;
        }
      }
    }
    int pix = (b * 16 + h) * 16 + w;
    f0_out[pix * 128 + cr] = f3;
    f0_out[pix * 128 + 64 + cr] = f5;
  }
}

// =====================  k2: fused Wd-gen + dynamic conv  =====================
// 512 blocks = 1 patch each. 512 threads = 8 waves.
// LDS: Ylds 32 KB + dyn 16.64 KB (scratch [64][65] f32 aliased with
//      8 x [32 ep][32 c] bf16 wave-private Wd regions).
__global__ __launch_bounds__(512, 4) void k2_fused(
    const float* __restrict__ y, const short* __restrict__ wlin_bf,
    const float* __restrict__ f0_in, const float* __restrict__ gs_in,
    const float* __restrict__ b_lin, float* __restrict__ out)
{
  __shared__ __align__(16) short Ylds[16384];   // [pix][32 granules of 8c]
  __shared__ __align__(16) char dyn[16640];
  float* scratch = (float*)dyn;                 // [64 c][65] f32 (staging)
  short* wdbase = (short*)dyn;                  // 8 x [32 ep][32 c] bf16

  int phys = blockIdx.x;
  int blk = (phys & 7) * 64 + (phys >> 3);      // XCD-contiguous patches
  int b = blk >> 8, f = (blk >> 4) & 15, g = blk & 15;
  int tid = threadIdx.x;
  int wave = tid >> 6, lane = tid & 63;
  int quad = lane >> 4, l16 = lane & 15;
  int geff = l16 & 7, jsel = l16 >> 3;

  const float* yb = y + b * 4194304 + (f * 8) * 128 + g * 8;

  // ---- y loads: 2 rounds in flight (depth-2 double buffer) ----
  int c32 = tid >> 4, pf = tid & 15;            // 32 c x 16 pixel-float4
  float4 yv[2][2];
  #pragma unroll
  for (int s = 0; s < 2; ++s)
    #pragma unroll
    for (int it = 0; it < 2; ++it)
      yv[s][it] = *(const float4*)(yb + (s * 64 + it * 32 + c32) * 16384 + (pf >> 1) * 128 + (pf & 1) * 4);

  // ---- wlin + b_lin prefetch for chunks 0,1 (slot = chunk&1) ----
  short8 aw[2][2][2];                           // [slot][jj][hh]
  float4 bl[2][2][2];
  #pragma unroll
  for (int s = 0; s < 2; ++s)
    #pragma unroll
    for (int jj = 0; jj < 2; ++jj) {
      int jA = wave * 4 + jj * 2 + (quad >> 1);
      int jD = wave * 4 + jj * 2 + jsel;
      #pragma unroll
      for (int hh = 0; hh < 2; ++hh) {
        int c0 = s * 32 + hh * 16;
        aw[s][jj][hh] = *(const short8*)(wlin_bf + (jA * 256 + c0 + l16) * 16 + (quad & 1) * 8);
        bl[s][jj][hh] = *(const float4*)(b_lin + jD * 256 + c0 + quad * 4);
      }
    }

  // ---- f0/gs loads (packed into bx after staging) ----
  bool bval = (jsel == (quad >> 1));
  const float* f0p = f0_in + blk * 128 + geff * 16 + (quad & 1) * 8;
  const float* gsp = gs_in + blk * 128 + geff * 16 + (quad & 1) * 8;
  float4 f0a = *(const float4*)f0p, f0b = *(const float4*)(f0p + 4);
  float4 gsa = *(const float4*)gsp, gsb = *(const float4*)(gsp + 4);

  // ---- stage Y: 4 rounds of 64 channels through scratch ----
  #pragma unroll
  for (int sch = 0; sch < 4; ++sch) {
    #pragma unroll
    for (int it = 0; it < 2; ++it)
      *(float4*)&scratch[(it * 32 + c32) * 65 + pf * 4] = yv[sch & 1][it];
    if (sch < 2) {                              // issue round sch+2 loads
      #pragma unroll
      for (int it = 0; it < 2; ++it)
        yv[sch & 1][it] = *(const float4*)(yb + ((sch + 2) * 64 + it * 32 + c32) * 16384 + (pf >> 1) * 128 + (pf & 1) * 4);
    }
    __syncthreads();
    {
      int pix = tid & 63, cg = tid >> 6;        // 64 pix x 8 c-groups of 8
      float s0 = scratch[(cg * 8 + 0) * 65 + pix];
      float s1 = scratch[(cg * 8 + 1) * 65 + pix];
      float s2 = scratch[(cg * 8 + 2) * 65 + pix];
      float s3 = scratch[(cg * 8 + 3) * 65 + pix];
      float s4 = scratch[(cg * 8 + 4) * 65 + pix];
      float s5 = scratch[(cg * 8 + 5) * 65 + pix];
      float s6 = scratch[(cg * 8 + 6) * 65 + pix];
      float s7 = scratch[(cg * 8 + 7) * 65 + pix];
      uint4 pk;
      pk.x = pk2bf(s0, s1); pk.y = pk2bf(s2, s3);
      pk.z = pk2bf(s4, s5); pk.w = pk2bf(s6, s7);
      int chunk = sch * 8 + cg;                 // 8-ch group id [0,32)
      int physc = chunk ^ (pix & 15);           // read-optimal swizzle
      *(uint4*)&Ylds[pix * 256 + physc * 8] = pk;
    }
    __syncthreads();
  }

  // ---- xc fragment: B[k][n=jsel*8+geff] = xc[geff][k%16] iff k>>4==jsel ----
  short8 bx = {0, 0, 0, 0, 0, 0, 0, 0};
  if (bval) {
    bx[0] = (short)f2bf(f0a.x * gsa.x); bx[1] = (short)f2bf(f0a.y * gsa.y);
    bx[2] = (short)f2bf(f0a.z * gsa.z); bx[3] = (short)f2bf(f0a.w * gsa.w);
    bx[4] = (short)f2bf(f0b.x * gsb.x); bx[5] = (short)f2bf(f0b.y * gsb.y);
    bx[6] = (short)f2bf(f0b.z * gsb.z); bx[7] = (short)f2bf(f0b.w * gsb.w);
  }

  f32x4 acc[2][4];
  #pragma unroll
  for (int et = 0; et < 2; ++et)
    #pragma unroll
    for (int nt = 0; nt < 4; ++nt)
      acc[et][nt] = {0.f, 0.f, 0.f, 0.f};

  // ---- per-wave Wd region: [32 ep][32 c] bf16, ep = geff*4 + jj*2 + jsel ----
  short* wdw = wdbase + wave * 1024;

  // gen: wave w produces jD = 4w + jj*2 + jsel (all 8 geff) -- wave-private.
  auto gen_chunk = [&](int cc, int slot) {
    #pragma unroll
    for (int jj = 0; jj < 2; ++jj) {
      int ep = geff * 4 + jj * 2 + jsel;
      int gx = ((ep >> 2) & 3) ^ (ep & 3);
      #pragma unroll
      for (int hh = 0; hh < 2; ++hh) {
        float4 blv = bl[slot][jj][hh];
        f32x4 cin = {blv.x, blv.y, blv.z, blv.w};
        f32x4 d = __builtin_amdgcn_mfma_f32_16x16x32_bf16(aw[slot][jj][hh], bx, cin, 0, 0, 0);
        uint2 pk;
        pk.x = pk2bf(d[0], d[1]);
        pk.y = pk2bf(d[2], d[3]);
        int q16 = (hh * 2 + (quad >> 1)) ^ gx;
        *(uint2*)&wdw[ep * 32 + q16 * 8 + (quad & 1) * 4] = pk;
      }
    }
  };

  gen_chunk(0, 0);  // scratch alias free after last staging barrier

  // ---- BARRIER-FREE K-loop: per-wave DS ordering protects wdw reuse ----
  #pragma unroll
  for (int cc = 0; cc < 8; ++cc) {
    short8 A2[2], Bf[4];
    #pragma unroll
    for (int et = 0; et < 2; ++et) {
      int ep = (l16 & 7) * 4 + et * 2 + (l16 >> 3);
      int gx = ((ep >> 2) & 3) ^ (ep & 3);
      A2[et] = *(const short8*)&wdw[ep * 32 + (quad ^ gx) * 8];
    }
    int chunkY = cc * 4 + quad;
    #pragma unroll
    for (int nt = 0; nt < 4; ++nt) {
      int physc = chunkY ^ l16;                 // pix&15 == l16
      Bf[nt] = *(const short8*)&Ylds[(nt * 16 + l16) * 256 + physc * 8];
    }
    if (cc < 6) {                               // prefetch wlin+bias for cc+2
      #pragma unroll
      for (int jj = 0; jj < 2; ++jj) {
        int jA = wave * 4 + jj * 2 + (quad >> 1);
        int jD = wave * 4 + jj * 2 + jsel;
        #pragma unroll
        for (int hh = 0; hh < 2; ++hh) {
          int c0 = (cc + 2) * 32 + hh * 16;
          aw[cc & 1][jj][hh] = *(const short8*)(wlin_bf + (jA * 256 + c0 + l16) * 16 + (quad & 1) * 8);
          bl[cc & 1][jj][hh] = *(const float4*)(b_lin + jD * 256 + c0 + quad * 4);
        }
      }
    }
    if (cc < 7) gen_chunk(cc + 1, (cc + 1) & 1);  // DS in-order: after A2 reads
    #pragma unroll
    for (int et = 0; et < 2; ++et)
      #pragma unroll
      for (int nt = 0; nt < 4; ++nt)
        acc[et][nt] = __builtin_amdgcn_mfma_f32_16x16x32_bf16(A2[et], Bf[nt], acc[et][nt], 0, 0, 0);
  }

  // ---- epilogue: lane row m=quad*4+r -> e=(m&7)*32+4*wave+et*2+(m>>3) ----
  float* ob = out + b * 4194304 + (f * 8) * 128 + g * 8;
  #pragma unroll
  for (int et = 0; et < 2; ++et) {
    #pragma unroll
    for (int nt = 0; nt < 4; ++nt) {
      int pix = nt * 16 + l16;
      float* oa = ob + (pix >> 3) * 128 + (pix & 7);
      #pragma unroll
      for (int r = 0; r < 4; ++r) {
        int m = quad * 4 + r;
        int e = (m & 7) * 32 + wave * 4 + et * 2 + (m >> 3);
        oa[e * 16384] = acc[et][nt][r];
      }
    }
  }
}

// ============================  launcher  ============================
extern "C" void kernel_launch(void* const* d_in, const int* in_sizes, int n_in,
                              void* d_out, int out_size, void* d_ws, size_t ws_size,
                              hipStream_t stream) {
  const float* x        = (const float*)d_in[0];
  const float* y        = (const float*)d_in[1];
  const float* w_cr     = (const float*)d_in[2];
  const float* b_cr     = (const float*)d_in[3];
  const float* w_dw3    = (const float*)d_in[4];
  const float* b_dw3    = (const float*)d_in[5];
  const float* w_dw7    = (const float*)d_in[6];
  const float* b_dw7    = (const float*)d_in[7];
  const float* w_gate   = (const float*)d_in[8];
  const float* b_gate   = (const float*)d_in[9];
  const float* bn_gamma = (const float*)d_in[10];
  const float* bn_beta  = (const float*)d_in[11];
  const float* bn_mean  = (const float*)d_in[12];
  const float* bn_var   = (const float*)d_in[13];
  const float* sr_scale = (const float*)d_in[14];
  const float* sr_bias  = (const float*)d_in[15];
  const float* w_lin    = (const float*)d_in[16];
  const float* b_lin    = (const float*)d_in[17];
  float* out = (float*)d_out;

  // ws layout: f0 256KB | gs 256KB | wlin_bf 256KB
  float* f0      = (float*)d_ws;
  float* gs      = (float*)((char*)d_ws + 262144);
  short* wlin_bf = (short*)((char*)d_ws + 524288);

  hipLaunchKernelGGL(k1_merged, dim3(640), dim3(256), 0, stream,
                     x, w_cr, b_cr, w_dw3, b_dw3, w_dw7, b_dw7, w_gate, b_gate,
                     bn_gamma, bn_beta, bn_mean, bn_var, sr_scale, sr_bias,
                     w_lin, wlin_bf, f0, gs);
  hipLaunchKernelGGL(k2_fused, dim3(512), dim3(512), 0, stream,
                     y, wlin_bf, f0, gs, b_lin, out);
}